// Round 1
// baseline (35001.996 us; speedup 1.0000x reference)
//
#include <hip/hip_runtime.h>
#include <hip/hip_bf16.h>

// Problem dims (fixed by reference). All global I/O is fp32.
#define BATCH 1024
#define DLAT  512
#define HHID  1024
#define TPTS  64
#define BD    (BATCH * DLAT)     // 524288

// Cooperative decomposition: 16 row-groups (64 rows) x 16 col-groups.
#define NBLK 256
#define NTHR 512                 // 8 waves
#define RGN  16                  // blocks per row-group (and # col groups)

typedef __attribute__((ext_vector_type(8))) short short8;  // 8 bf16 (4 VGPRs)
typedef __attribute__((ext_vector_type(4))) float f32x4;   // MFMA C/D frag

__device__ __forceinline__ short f2bf(float x) {
    __hip_bfloat16 h = __float2bfloat16(x);
    return __builtin_bit_cast(short, h);
}
__device__ __forceinline__ float fast_tanh(float x) {
    // clamped exp-based tanh: |err| ~1e-7; clamp also kills any NaN/Inf
    x = fminf(9.f, fmaxf(-9.f, x));
    const float e = __expf(2.f * x);
    return (e - 1.f) / (e + 1.f);
}

// Row-group barrier: 16 blocks, monotonic generation counter.
// Writer side: all threads fence (release) before tid0 signals.
// Reader side: tid0 spins, then all threads fence (acquire).
__device__ __forceinline__ void rg_barrier(int* bar, int cidx, int target, int tid)
{
    __threadfence();          // release: flush this block's global writes
    __syncthreads();
    if (tid == 0) {
        atomicAdd(&bar[cidx], 1);
        while (__hip_atomic_load(&bar[cidx], __ATOMIC_RELAXED,
                                 __HIP_MEMORY_SCOPE_AGENT) < target) {
            __builtin_amdgcn_s_sleep(2);
        }
    }
    __syncthreads();
    __threadfence();          // acquire: invalidate stale cached lines
}

// ---------------------------------------------------------------------------
// Cooperative persistent ODE kernel.
//   block(rg,cg): rows [rg*64, rg*64+64), phase-A H-cols [cg*64,+64),
//                 phase-B z-cols [cg*32,+32).
//   W1 slice [512 x 64] + W2 slice [1024 x 32] live in LDS all 252 stages.
//   Exchange buffers (global, bf16 MFMA-A fragment order):
//     zf: [64 row-tiles][16 k-tiles][64 lanes][8]   (1 MB)
//     Hf: [64 row-tiles][32 k-tiles][64 lanes][8]   (2 MB)
// mfma_f32_16x16x32_bf16 layouts (m89/m120-verified):
//   A[m=lane&15][k=(lane>>4)*8+j], B[k=(lane>>4)*8+j][n=lane&15]
//   C/D: col=lane&15, row=(lane>>4)*4+reg
// ---------------------------------------------------------------------------
__global__ __launch_bounds__(NTHR) void ode_coop(
    const float* __restrict__ z0, const float* __restrict__ t,
    const float* __restrict__ W1, const float* __restrict__ b1,
    const float* __restrict__ W2, const float* __restrict__ b2,
    short* __restrict__ zf, short* __restrict__ Hf,
    int* __restrict__ bar, float* __restrict__ traj)
{
    __shared__ __align__(16) short W1L[4 * 16 * 64 * 8];  // 64 KB [ct][kt][lane][j]
    __shared__ __align__(16) short W2L[2 * 32 * 64 * 8];  // 64 KB [ct2][kt2][lane][j]
    __shared__ __align__(16) short Hst[8 * 64 * 8];       //  8 KB [rt*2+k2l][lane][j]
    __shared__ __align__(16) short zst[4 * 64 * 8];       //  4 KB [rt][lane][j]
    __shared__ float b1L[64];
    __shared__ float b2L[32];

    const int tid  = threadIdx.x;
    const int lane = tid & 63;
    const int w    = tid >> 6;       // wave 0..7
    const int q    = lane >> 4;
    const int cl   = lane & 15;

    // XCD-cluster the 16 blocks of each row-group (heuristic: bid%8 = XCD).
    const int bid  = blockIdx.x;
    const int xcd  = bid & 7;
    const int slot = bid >> 3;                 // 0..31
    const int rg   = xcd * 2 + (slot >> 4);    // 0..15 row-group
    const int cg   = slot & 15;                // 0..15 col-group
    const int cidx = rg * 32;                  // 128B-spaced barrier counters

    // ---- one-time: weight slices fp32 -> bf16 fragment order -> LDS ----
    for (int i = tid; i < 4 * 16 * 64; i += NTHR) {
        const int ct = i >> 10, kt = (i >> 6) & 15, l = i & 63;
        const int k0 = kt * 32 + (l >> 4) * 8;
        const int n  = cg * 64 + ct * 16 + (l & 15);
        short8 v;
#pragma unroll
        for (int j = 0; j < 8; ++j) v[j] = f2bf(W1[(size_t)(k0 + j) * HHID + n]);
        *(short8*)&W1L[i * 8] = v;
    }
    for (int i = tid; i < 2 * 32 * 64; i += NTHR) {
        const int ct = i >> 11, kt = (i >> 6) & 31, l = i & 63;
        const int k0 = kt * 32 + (l >> 4) * 8;
        const int n  = cg * 32 + ct * 16 + (l & 15);
        short8 v;
#pragma unroll
        for (int j = 0; j < 8; ++j) v[j] = f2bf(W2[(size_t)(k0 + j) * DLAT + n]);
        *(short8*)&W2L[i * 8] = v;
    }
    if (tid < 64)      b1L[tid]      = b1[cg * 64 + tid];
    else if (tid < 96) b2L[tid - 64] = b2[cg * 32 + (tid - 64)];

    // ---- ownership ----
    // phase A: wave -> output tile rows rt=w>>1, H-col pair c0=(w&1)*2
    // phase B: wave -> output tile (rt=w>>1, ct2=w&1); thread owns 4 fp32 z elems
    const int rt   = w >> 1;
    const int c0   = (w & 1) * 2;
    const int ct2b = w & 1;
    const int rowb = rg * 64 + rt * 16 + q * 4;     // + reg = global batch row
    const int nb   = cg * 32 + ct2b * 16 + cl;      // global z col
    const int clb  = ct2b * 16 + cl;                // local z col 0..31
    const int zsti = rt * 512 + ((clb >> 3) * 16 + q * 4) * 8 + (clb & 7); // + reg*8

    float zreg[4], kacc[4];
#pragma unroll
    for (int reg = 0; reg < 4; ++reg) {
        const float zv = z0[(size_t)(rowb + reg) * DLAT + nb];
        zreg[reg] = zv;
        traj[(size_t)(rowb + reg) * DLAT + nb] = zv;    // traj[0] exact fp32
        zst[zsti + reg * 8] = f2bf(zv);
    }
    __syncthreads();
    if (tid < 256) {   // zst -> zf (block's 4 KB slice), 16B/thread
        const int rr = tid >> 6, l = tid & 63;
        *(short8*)&zf[((size_t)(rg * 4 + rr) * 16 + cg) * 512 + l * 8] =
            *(const short8*)&zst[tid * 8];
    }

    int target = 0;
    target += RGN; rg_barrier(bar, cidx, target, tid);

    const short* zrow = zf + (size_t)(rg * 4 + rt) * 8192  + lane * 8;
    const short* hrow = Hf + (size_t)(rg * 4 + rt) * 16384 + lane * 8;
    const short* w1p  = &W1L[c0 * 8192 + lane * 8];
    const short* w2p  = &W2L[ct2b * 16384 + lane * 8];

    for (int step = 0; step < TPTS - 1; ++step) {
        const float dt = t[step + 1] - t[step];
#pragma unroll
        for (int stage = 0; stage < 4; ++stage) {
            // ============== phase A: H = tanh(z @ W1slice + b1) ==============
            {
                f32x4 acc0 = {0.f, 0.f, 0.f, 0.f};
                f32x4 acc1 = {0.f, 0.f, 0.f, 0.f};
#pragma unroll
                for (int kt = 0; kt < 16; ++kt) {
                    const short8 a  = *(const short8*)(zrow + kt * 512);
                    const short8 bA = *(const short8*)(w1p + kt * 512);
                    const short8 bB = *(const short8*)(w1p + 8192 + kt * 512);
                    acc0 = __builtin_amdgcn_mfma_f32_16x16x32_bf16(a, bA, acc0, 0, 0, 0);
                    acc1 = __builtin_amdgcn_mfma_f32_16x16x32_bf16(a, bB, acc1, 0, 0, 0);
                }
#pragma unroll
                for (int c = 0; c < 2; ++c) {
                    const int   cloc = (c0 + c) * 16 + cl;    // 0..63
                    const float bb   = b1L[cloc];
                    const f32x4 av   = c ? acc1 : acc0;
#pragma unroll
                    for (int reg = 0; reg < 4; ++reg) {
                        Hst[(rt * 2 + (cloc >> 5)) * 512 +
                            (((cloc & 31) >> 3) * 16 + q * 4 + reg) * 8 + (cloc & 7)] =
                            f2bf(fast_tanh(av[reg] + bb));
                    }
                }
            }
            __syncthreads();
            {   // Hst -> Hf (block's 8 KB slice), 16B/thread
                const int rr = tid >> 7, k2l = (tid >> 6) & 1, l = tid & 63;
                *(short8*)&Hf[((size_t)(rg * 4 + rr) * 32 + cg * 2 + k2l) * 512 + l * 8] =
                    *(const short8*)&Hst[tid * 8];
            }
            target += RGN; rg_barrier(bar, cidx, target, tid);

            // ============ phase B: kv = H @ W2slice + b2 ; RK4 update ========
            {
                f32x4 acce = {0.f, 0.f, 0.f, 0.f};
                f32x4 acco = {0.f, 0.f, 0.f, 0.f};
#pragma unroll
                for (int kt = 0; kt < 32; kt += 2) {
                    const short8 a0  = *(const short8*)(hrow + kt * 512);
                    const short8 a1  = *(const short8*)(hrow + kt * 512 + 512);
                    const short8 bb0 = *(const short8*)(w2p + kt * 512);
                    const short8 bb1 = *(const short8*)(w2p + kt * 512 + 512);
                    acce = __builtin_amdgcn_mfma_f32_16x16x32_bf16(a0, bb0, acce, 0, 0, 0);
                    acco = __builtin_amdgcn_mfma_f32_16x16x32_bf16(a1, bb1, acco, 0, 0, 0);
                }
                const float bb = b2L[clb];
#pragma unroll
                for (int reg = 0; reg < 4; ++reg) {
                    const float kv = acce[reg] + acco[reg] + bb;
                    float znext;
                    if (stage == 0) {
                        kacc[reg] = kv;        znext = zreg[reg] + 0.5f * dt * kv;
                    } else if (stage == 1) {
                        kacc[reg] += 2.f * kv; znext = zreg[reg] + 0.5f * dt * kv;
                    } else if (stage == 2) {
                        kacc[reg] += 2.f * kv; znext = zreg[reg] + dt * kv;
                    } else {
                        zreg[reg] += (dt * (1.f / 6.f)) * (kacc[reg] + kv);
                        znext = zreg[reg];
                        traj[(size_t)(step + 1) * BD +
                             (size_t)(rowb + reg) * DLAT + nb] = znext;
                    }
                    zst[zsti + reg * 8] = f2bf(znext);
                }
            }
            __syncthreads();
            if (tid < 256) {   // zst -> zf
                const int rr = tid >> 6, l = tid & 63;
                *(short8*)&zf[((size_t)(rg * 4 + rr) * 16 + cg) * 512 + l * 8] =
                    *(const short8*)&zst[tid * 8];
            }
            target += RGN; rg_barrier(bar, cidx, target, tid);
        }
    }
}

// ---------------------------------------------------------------------------
extern "C" void kernel_launch(void* const* d_in, const int* in_sizes, int n_in,
                              void* d_out, int out_size, void* d_ws, size_t ws_size,
                              hipStream_t stream)
{
    (void)in_sizes; (void)n_in; (void)out_size; (void)ws_size;

    const float* z0 = (const float*)d_in[0];
    const float* t  = (const float*)d_in[1];
    const float* W1 = (const float*)d_in[2];
    const float* b1 = (const float*)d_in[3];
    const float* W2 = (const float*)d_in[4];
    const float* b2 = (const float*)d_in[5];
    float*       traj = (float*)d_out;

    // Workspace: zf (1 MB) | Hf (2 MB) | barrier counters (2 KB)  = 3.01 MB
    short* zf  = (short*)d_ws;
    short* Hf  = (short*)((char*)d_ws + (1u << 20));
    int*   bar = (int*)((char*)d_ws + (3u << 20));

    hipMemsetAsync(bar, 0, 16 * 32 * sizeof(int), stream);

    void* args[] = {&z0, &t, &W1, &b1, &W2, &b2, &zf, &Hf, &bar, &traj};
    hipLaunchCooperativeKernel((const void*)ode_coop, dim3(NBLK), dim3(NTHR),
                               args, 0, stream);
}

// Round 2
// 1398.254 us; speedup vs baseline: 25.0326x; 25.0326x over previous
//
#include <hip/hip_runtime.h>
#include <hip/hip_bf16.h>

// Problem dims (fixed by reference). All global I/O is fp32.
#define BATCH 1024
#define DLAT  512
#define HHID  1024
#define TPTS  64
#define BD    (BATCH * DLAT)     // 524288

// Cooperative decomposition: 16 row-groups (64 rows) x 16 col-groups.
// 256 blocks @ 140 KB LDS -> exactly 1 block/CU -> exactly 32 blocks/XCD.
#define NBLK 256
#define NTHR 512                 // 8 waves
#define RGN  16                  // blocks per row-group (and # col groups)

typedef __attribute__((ext_vector_type(8))) short short8;  // 8 bf16 (4 VGPRs)
typedef __attribute__((ext_vector_type(4))) float f32x4;   // MFMA C/D frag

__device__ __forceinline__ short f2bf(float x) {
    __hip_bfloat16 h = __float2bfloat16(x);
    return __builtin_bit_cast(short, h);
}
__device__ __forceinline__ float fast_tanh(float x) {
    // clamped exp-based tanh: |err| ~1e-7; clamp also kills any NaN/Inf
    x = fminf(9.f, fmaxf(-9.f, x));
    const float e = __expf(2.f * x);
    return (e - 1.f) / (e + 1.f);
}

// Row-group barrier for 16 SAME-XCD blocks. Coherence point = the XCD's L2.
// Release: __syncthreads already drains vmcnt(0) (stores are in L2 -- L1 is
//          write-through), then tid0 bumps the device-scope counter.
// Acquire: invalidate per-CU vector L1 ONLY (buffer_inv, ~free) so exchange
//          loads re-read the XCD-local L2. NO __threadfence: device-scope
//          fences emit buffer_wbl2 + L2-invalidate, which was round-1's
//          910 MB HBM writeback / 139 us-per-stage disaster.
__device__ __forceinline__ void rg_barrier(int* bar, int cidx, int target, int tid)
{
    __syncthreads();             // s_waitcnt vmcnt(0) lgkmcnt(0) + s_barrier
    if (tid == 0) {
        atomicAdd(&bar[cidx], 1);
        while (__hip_atomic_load(&bar[cidx], __ATOMIC_RELAXED,
                                 __HIP_MEMORY_SCOPE_AGENT) < target) {
            __builtin_amdgcn_s_sleep(2);
        }
    }
    __syncthreads();
    asm volatile("buffer_inv\n\ts_waitcnt vmcnt(0)" ::: "memory");  // L1 inv
}

// ---------------------------------------------------------------------------
// Cooperative persistent ODE kernel.
//   block(rg,cg): rows [rg*64, rg*64+64), phase-A H-cols [cg*64,+64),
//                 phase-B z-cols [cg*32,+32).  rg is XCD-local by construction.
//   W1 slice [512 x 64] + W2 slice [1024 x 32] live in LDS all 252 stages.
//   Exchange buffers (global, bf16 MFMA-A fragment order, XCD-L2 resident):
//     zf: [64 row-tiles][16 k-tiles][64 lanes][8]   (1 MB)
//     Hf: [64 row-tiles][32 k-tiles][64 lanes][8]   (2 MB)
// mfma_f32_16x16x32_bf16 layouts (m89/m120-verified):
//   A[m=lane&15][k=(lane>>4)*8+j], B[k=(lane>>4)*8+j][n=lane&15]
//   C/D: col=lane&15, row=(lane>>4)*4+reg
// ---------------------------------------------------------------------------
__global__ __launch_bounds__(NTHR) void ode_coop(
    const float* __restrict__ z0, const float* __restrict__ t,
    const float* __restrict__ W1, const float* __restrict__ b1,
    const float* __restrict__ W2, const float* __restrict__ b2,
    short* __restrict__ zf, short* __restrict__ Hf,
    int* __restrict__ bar, int* __restrict__ xcnt,
    float* __restrict__ traj)
{
    __shared__ __align__(16) short W1L[4 * 16 * 64 * 8];  // 64 KB [ct][kt][lane][j]
    __shared__ __align__(16) short W2L[2 * 32 * 64 * 8];  // 64 KB [ct2][kt2][lane][j]
    __shared__ __align__(16) short Hst[8 * 64 * 8];       //  8 KB [rt*2+k2l][lane][j]
    __shared__ __align__(16) short zst[4 * 64 * 8];       //  4 KB [rt][lane][j]
    __shared__ float b1L[64];
    __shared__ float b2L[32];
    __shared__ int slotS;

    const int tid  = threadIdx.x;
    const int lane = tid & 63;
    const int w    = tid >> 6;       // wave 0..7
    const int q    = lane >> 4;
    const int cl   = lane & 15;

    // ---- role assignment from the REAL XCD id (same-XCD rg by construction) ----
    unsigned int xcc;
    asm("s_getreg_b32 %0, hwreg(HW_REG_XCC_ID)" : "=s"(xcc));
    xcc &= 7u;
    if (tid == 0) slotS = atomicAdd(&xcnt[xcc], 1);
    __syncthreads();
    const int slot = slotS & 31;               // 0..31 within this XCD
    const int rg   = (int)xcc * 2 + (slot >> 4);   // 0..15 row-group (XCD-local)
    const int cg   = slot & 15;                // 0..15 col-group
    const int cidx = rg * 32;                  // 128B-spaced barrier counters

    // ---- one-time: weight slices fp32 -> bf16 fragment order -> LDS ----
    for (int i = tid; i < 4 * 16 * 64; i += NTHR) {
        const int ct = i >> 10, kt = (i >> 6) & 15, l = i & 63;
        const int k0 = kt * 32 + (l >> 4) * 8;
        const int n  = cg * 64 + ct * 16 + (l & 15);
        short8 v;
#pragma unroll
        for (int j = 0; j < 8; ++j) v[j] = f2bf(W1[(size_t)(k0 + j) * HHID + n]);
        *(short8*)&W1L[i * 8] = v;
    }
    for (int i = tid; i < 2 * 32 * 64; i += NTHR) {
        const int ct = i >> 11, kt = (i >> 6) & 31, l = i & 63;
        const int k0 = kt * 32 + (l >> 4) * 8;
        const int n  = cg * 32 + ct * 16 + (l & 15);
        short8 v;
#pragma unroll
        for (int j = 0; j < 8; ++j) v[j] = f2bf(W2[(size_t)(k0 + j) * DLAT + n]);
        *(short8*)&W2L[i * 8] = v;
    }
    if (tid < 64)      b1L[tid]      = b1[cg * 64 + tid];
    else if (tid < 96) b2L[tid - 64] = b2[cg * 32 + (tid - 64)];

    // ---- ownership ----
    // phase A: wave -> output tile rows rt=w>>1, H-col pair c0=(w&1)*2
    // phase B: wave -> output tile (rt=w>>1, ct2=w&1); thread owns 4 fp32 z elems
    const int rt   = w >> 1;
    const int c0   = (w & 1) * 2;
    const int ct2b = w & 1;
    const int rowb = rg * 64 + rt * 16 + q * 4;     // + reg = global batch row
    const int nb   = cg * 32 + ct2b * 16 + cl;      // global z col
    const int clb  = ct2b * 16 + cl;                // local z col 0..31
    const int zsti = rt * 512 + ((clb >> 3) * 16 + q * 4) * 8 + (clb & 7); // + reg*8

    float zreg[4], kacc[4];
#pragma unroll
    for (int reg = 0; reg < 4; ++reg) {
        const float zv = z0[(size_t)(rowb + reg) * DLAT + nb];
        zreg[reg] = zv;
        traj[(size_t)(rowb + reg) * DLAT + nb] = zv;    // traj[0] exact fp32
        zst[zsti + reg * 8] = f2bf(zv);
    }
    __syncthreads();
    if (tid < 256) {   // zst -> zf (block's 4 KB slice), 16B/thread
        const int rr = tid >> 6, l = tid & 63;
        *(short8*)&zf[((size_t)(rg * 4 + rr) * 16 + cg) * 512 + l * 8] =
            *(const short8*)&zst[tid * 8];
    }

    int target = 0;
    target += RGN; rg_barrier(bar, cidx, target, tid);

    const short* zrow = zf + (size_t)(rg * 4 + rt) * 8192  + lane * 8;
    const short* hrow = Hf + (size_t)(rg * 4 + rt) * 16384 + lane * 8;
    const short* w1p  = &W1L[c0 * 8192 + lane * 8];
    const short* w2p  = &W2L[ct2b * 16384 + lane * 8];

    for (int step = 0; step < TPTS - 1; ++step) {
        const float dt = t[step + 1] - t[step];
#pragma unroll
        for (int stage = 0; stage < 4; ++stage) {
            // ============== phase A: H = tanh(z @ W1slice + b1) ==============
            {
                f32x4 acc0 = {0.f, 0.f, 0.f, 0.f};
                f32x4 acc1 = {0.f, 0.f, 0.f, 0.f};
#pragma unroll
                for (int kt = 0; kt < 16; ++kt) {
                    const short8 a  = *(const short8*)(zrow + kt * 512);
                    const short8 bA = *(const short8*)(w1p + kt * 512);
                    const short8 bB = *(const short8*)(w1p + 8192 + kt * 512);
                    acc0 = __builtin_amdgcn_mfma_f32_16x16x32_bf16(a, bA, acc0, 0, 0, 0);
                    acc1 = __builtin_amdgcn_mfma_f32_16x16x32_bf16(a, bB, acc1, 0, 0, 0);
                }
#pragma unroll
                for (int c = 0; c < 2; ++c) {
                    const int   cloc = (c0 + c) * 16 + cl;    // 0..63
                    const float bb   = b1L[cloc];
                    const f32x4 av   = c ? acc1 : acc0;
#pragma unroll
                    for (int reg = 0; reg < 4; ++reg) {
                        Hst[(rt * 2 + (cloc >> 5)) * 512 +
                            (((cloc & 31) >> 3) * 16 + q * 4 + reg) * 8 + (cloc & 7)] =
                            f2bf(fast_tanh(av[reg] + bb));
                    }
                }
            }
            __syncthreads();
            {   // Hst -> Hf (block's 8 KB slice), 16B/thread
                const int rr = tid >> 7, k2l = (tid >> 6) & 1, l = tid & 63;
                *(short8*)&Hf[((size_t)(rg * 4 + rr) * 32 + cg * 2 + k2l) * 512 + l * 8] =
                    *(const short8*)&Hst[tid * 8];
            }
            target += RGN; rg_barrier(bar, cidx, target, tid);

            // ============ phase B: kv = H @ W2slice + b2 ; RK4 update ========
            {
                f32x4 acce = {0.f, 0.f, 0.f, 0.f};
                f32x4 acco = {0.f, 0.f, 0.f, 0.f};
#pragma unroll
                for (int kt = 0; kt < 32; kt += 2) {
                    const short8 a0  = *(const short8*)(hrow + kt * 512);
                    const short8 a1  = *(const short8*)(hrow + kt * 512 + 512);
                    const short8 bb0 = *(const short8*)(w2p + kt * 512);
                    const short8 bb1 = *(const short8*)(w2p + kt * 512 + 512);
                    acce = __builtin_amdgcn_mfma_f32_16x16x32_bf16(a0, bb0, acce, 0, 0, 0);
                    acco = __builtin_amdgcn_mfma_f32_16x16x32_bf16(a1, bb1, acco, 0, 0, 0);
                }
                const float bb = b2L[clb];
#pragma unroll
                for (int reg = 0; reg < 4; ++reg) {
                    const float kv = acce[reg] + acco[reg] + bb;
                    float znext;
                    if (stage == 0) {
                        kacc[reg] = kv;        znext = zreg[reg] + 0.5f * dt * kv;
                    } else if (stage == 1) {
                        kacc[reg] += 2.f * kv; znext = zreg[reg] + 0.5f * dt * kv;
                    } else if (stage == 2) {
                        kacc[reg] += 2.f * kv; znext = zreg[reg] + dt * kv;
                    } else {
                        zreg[reg] += (dt * (1.f / 6.f)) * (kacc[reg] + kv);
                        znext = zreg[reg];
                        traj[(size_t)(step + 1) * BD +
                             (size_t)(rowb + reg) * DLAT + nb] = znext;
                    }
                    zst[zsti + reg * 8] = f2bf(znext);
                }
            }
            __syncthreads();
            if (tid < 256) {   // zst -> zf
                const int rr = tid >> 6, l = tid & 63;
                *(short8*)&zf[((size_t)(rg * 4 + rr) * 16 + cg) * 512 + l * 8] =
                    *(const short8*)&zst[tid * 8];
            }
            target += RGN; rg_barrier(bar, cidx, target, tid);
        }
    }
}

// ---------------------------------------------------------------------------
extern "C" void kernel_launch(void* const* d_in, const int* in_sizes, int n_in,
                              void* d_out, int out_size, void* d_ws, size_t ws_size,
                              hipStream_t stream)
{
    (void)in_sizes; (void)n_in; (void)out_size; (void)ws_size;

    const float* z0 = (const float*)d_in[0];
    const float* t  = (const float*)d_in[1];
    const float* W1 = (const float*)d_in[2];
    const float* b1 = (const float*)d_in[3];
    const float* W2 = (const float*)d_in[4];
    const float* b2 = (const float*)d_in[5];
    float*       traj = (float*)d_out;

    // Workspace: zf (1 MB) | Hf (2 MB) | bar (2 KB) | xcnt (32 B)
    short* zf   = (short*)d_ws;
    short* Hf   = (short*)((char*)d_ws + (1u << 20));
    int*   bar  = (int*)((char*)d_ws + (3u << 20));
    int*   xcnt = (int*)((char*)d_ws + (3u << 20) + 2048);

    hipMemsetAsync(bar, 0, 16 * 32 * sizeof(int) + 8 * sizeof(int), stream);

    void* args[] = {&z0, &t, &W1, &b1, &W2, &b2, &zf, &Hf, &bar, &xcnt, &traj};
    hipLaunchCooperativeKernel((const void*)ode_coop, dim3(NBLK), dim3(NTHR),
                               args, 0, stream);
}